// Round 5
// baseline (142.586 us; speedup 1.0000x reference)
//
#include <hip/hip_runtime.h>

// PatchMask fused single-kernel, clustered unroll x4:
//   out[b,c,t] = x[b,c,t] * (bit(c*NP + t/PATCH) ? 0 : 1)
// B=128, C=128, T=5000, PATCH=25, NP=200, UNITS=25600, NMASK=2560

#define PM_B 128
#define PM_C 128
#define PM_T 5000
#define PM_PATCH 25
#define PM_NP 200                      // PM_T / PM_PATCH
#define PM_UNITS (PM_C * PM_NP)        // 25600
#define PM_NMASK 2560
#define PM_F4_PER_ROW (PM_T / 4)       // 1250
#define PM_F4_TOTAL (PM_B * PM_C * PM_F4_PER_ROW)  // 20,480,000
#define PM_MWORDS (PM_UNITS / 32)      // 800

typedef float f32x4 __attribute__((ext_vector_type(4)));

__device__ __forceinline__ f32x4 pm_mask_mul(
    unsigned i, f32x4 v, const unsigned* mbits)
{
    const unsigned row = i / PM_F4_PER_ROW;            // b*C + c (magic-mul)
    const unsigned t0  = (i - row * PM_F4_PER_ROW) * 4u;
    const unsigned cbase = (row & (PM_C - 1)) * PM_NP;

    const unsigned p0 = t0 / PM_PATCH;
    const unsigned p3 = (t0 + 3u) / PM_PATCH;
    const unsigned u0 = cbase + p0;
    const float m0 = ((mbits[u0 >> 5] >> (u0 & 31u)) & 1u) ? 0.0f : 1.0f;
    if (p0 == p3) {
        v *= m0;
    } else {
        const unsigned u3 = cbase + p3;
        const float m3 = ((mbits[u3 >> 5] >> (u3 & 31u)) & 1u) ? 0.0f : 1.0f;
        const unsigned boundary = p3 * PM_PATCH;       // first t in patch p3
        v.x *= (t0 + 0u < boundary) ? m0 : m3;
        v.y *= (t0 + 1u < boundary) ? m0 : m3;
        v.z *= (t0 + 2u < boundary) ? m0 : m3;
        v.w *= (t0 + 3u < boundary) ? m0 : m3;
    }
    return v;
}

__global__ __launch_bounds__(256) void pm_fused(
    const f32x4* __restrict__ x,
    const int* __restrict__ idx,
    f32x4* __restrict__ out)
{
    __shared__ unsigned mbits[PM_MWORDS];              // 3.2 KB

    for (unsigned w = threadIdx.x; w < PM_MWORDS; w += 256u)
        mbits[w] = 0u;
    __syncthreads();
    for (unsigned j = threadIdx.x; j < PM_NMASK; j += 256u) {
        const unsigned u = (unsigned)idx[j];
        atomicOr(&mbits[u >> 5], 1u << (u & 31u));
    }
    __syncthreads();

    const unsigned stride = gridDim.x * 256u;
    unsigned i = blockIdx.x * 256u + threadIdx.x;

    // Clustered unroll x4: issue 4 nt-loads back-to-back (4 outstanding VMEM
    // per wave), then 4 mask+nt-stores. Deepens MLP vs load->store chains.
    for (; i + 3u * stride < PM_F4_TOTAL; i += 4u * stride) {
        const unsigned i0 = i, i1 = i + stride, i2 = i + 2u * stride, i3 = i + 3u * stride;
        f32x4 v0 = __builtin_nontemporal_load(x + i0);
        f32x4 v1 = __builtin_nontemporal_load(x + i1);
        f32x4 v2 = __builtin_nontemporal_load(x + i2);
        f32x4 v3 = __builtin_nontemporal_load(x + i3);
        v0 = pm_mask_mul(i0, v0, mbits);
        v1 = pm_mask_mul(i1, v1, mbits);
        v2 = pm_mask_mul(i2, v2, mbits);
        v3 = pm_mask_mul(i3, v3, mbits);
        __builtin_nontemporal_store(v0, out + i0);
        __builtin_nontemporal_store(v1, out + i1);
        __builtin_nontemporal_store(v2, out + i2);
        __builtin_nontemporal_store(v3, out + i3);
    }
    for (; i < PM_F4_TOTAL; i += stride) {
        f32x4 v = __builtin_nontemporal_load(x + i);
        v = pm_mask_mul(i, v, mbits);
        __builtin_nontemporal_store(v, out + i);
    }
}

extern "C" void kernel_launch(void* const* d_in, const int* in_sizes, int n_in,
                              void* d_out, int out_size, void* d_ws, size_t ws_size,
                              hipStream_t stream) {
    const float* x   = (const float*)d_in[0];
    const int*   idx = (const int*)d_in[1];
    float*       out = (float*)d_out;

    // 2048 blocks x 256 threads = 8 blocks/CU = 32 waves/CU (max occupancy)
    pm_fused<<<2048, 256, 0, stream>>>(
        (const f32x4*)x, idx, (f32x4*)out);
}